// Round 1
// baseline (7624.223 us; speedup 1.0000x reference)
//
#include <hip/hip_runtime.h>

#define BB 128
#define TT 64
#define DD 300
#define HH 512
#define G4 2048
#define KL 812          // D + H
#define NEGV (-10000.0f)

__device__ __forceinline__ float4 ld4(const float* p) { return *(const float4*)p; }
__device__ __forceinline__ float sigm(float x) { return 1.0f / (1.0f + expf(-x)); }

struct GP {
  const float* emb;
  const int* tok1; const int* tok2;
  const float* W1; const float* W2;
  const float* Bp;
  float* hbuf; float* Ybuf; float* rbuf; float* rfin;
  float* Cout;
  int t; int K; int ldb; int ldc;
};

// Tiled fp32 GEMM, 64x64 output tile, BK=16, 256 threads (16x16, 4x4 per thread).
// MODE 0: LSTM step gates   A=[emb_gather | h]  (K=812), B=W1/W2 (per run z), C=gates[split][run]
// MODE 1: attn step         A=[Y2[:,t,:] | r]   (K=1024), B=Bpack, C=uv[split][asym]
// MODE 2: WyY               A=Y(premise run)    (K=512),  B=Wy,    C=WyY[asym]
// MODE 3: final la/lb       A=[rfin | last_h]   (K=1024), B=Wpx,   C=tanh(...)->lalb[asym]
template<int MODE, int S>
__global__ __launch_bounds__(256) void gemm64(GP p) {
  const int bz = blockIdx.z;
  const int z = bz / S, split = bz % S;
  const int n0 = blockIdx.x << 6;
  const int m0 = blockIdx.y << 6;
  const int tid = threadIdx.x;
  const int tx = tid & 15, ty = tid >> 4;
  const int arow = tid >> 2, kq = tid & 3;
  const int brow = m0 + arow;

  __shared__ __align__(16) float As[16][76];  // [k][row], stride 76 -> aligned b128 reads, 2-way write conflicts only
  __shared__ __align__(16) float Bs[16][64];  // [k][col]
  float acc[4][4] = {};

  const float* Bsrc = p.Bp;
  int token = 0;
  if constexpr (MODE == 0) {
    const int* tok = (z == 0 || z == 3) ? p.tok1 : p.tok2;
    token = tok[brow * TT + p.t];
    Bsrc = (z & 1) ? p.W2 : p.W1;
  }

  const int nch = (p.K + 15) >> 4;
  const int per = (nch + S - 1) / S;
  const int c0 = split * per;
  const int c1 = (c0 + per < nch) ? (c0 + per) : nch;

  for (int ch = c0; ch < c1; ++ch) {
    const int k0 = ch << 4;
    // ---- A fragment (this thread: row brow, k = k4..k4+3) ----
    float4 av = make_float4(0.f, 0.f, 0.f, 0.f);
    const int k4 = k0 + (kq << 2);
    if constexpr (MODE == 0) {
      if (k4 < DD)       av = ld4(&p.emb[(size_t)token * DD + k4]);
      else if (k4 < KL)  av = ld4(&p.hbuf[(size_t)(z * BB + brow) * HH + (k4 - DD)]);
    } else if constexpr (MODE == 1) {
      if (k4 < HH) av = ld4(&p.Ybuf[(size_t)(((z ? 3 : 1) * BB + brow) * TT + p.t) * HH + k4]);
      else         av = ld4(&p.rbuf[(size_t)(z * BB + brow) * HH + (k4 - HH)]);
    } else if constexpr (MODE == 2) {
      av = ld4(&p.Ybuf[(size_t)(z ? 2 : 0) * (BB * TT * HH) + (size_t)brow * HH + k4]);
    } else {
      if (k4 < HH) av = ld4(&p.rfin[(size_t)(z * BB + brow) * HH + k4]);
      else         av = ld4(&p.hbuf[(size_t)((z ? 3 : 1) * BB + brow) * HH + (k4 - HH)]);
    }
    // ---- B fragment ----
    float4 bv = make_float4(0.f, 0.f, 0.f, 0.f);
    const int bk = k0 + ty;
    if (bk < p.K) bv = ld4(&Bsrc[(size_t)bk * p.ldb + n0 + (tx << 2)]);

    __syncthreads();
    As[(kq << 2) + 0][arow] = av.x;
    As[(kq << 2) + 1][arow] = av.y;
    As[(kq << 2) + 2][arow] = av.z;
    As[(kq << 2) + 3][arow] = av.w;
    *(float4*)&Bs[ty][tx << 2] = bv;
    __syncthreads();

#pragma unroll
    for (int k = 0; k < 16; ++k) {
      const float4 a4 = *(const float4*)&As[k][ty << 2];
      const float4 b4 = *(const float4*)&Bs[k][tx << 2];
      acc[0][0] += a4.x * b4.x; acc[0][1] += a4.x * b4.y; acc[0][2] += a4.x * b4.z; acc[0][3] += a4.x * b4.w;
      acc[1][0] += a4.y * b4.x; acc[1][1] += a4.y * b4.y; acc[1][2] += a4.y * b4.z; acc[1][3] += a4.y * b4.w;
      acc[2][0] += a4.z * b4.x; acc[2][1] += a4.z * b4.y; acc[2][2] += a4.z * b4.z; acc[2][3] += a4.z * b4.w;
      acc[3][0] += a4.w * b4.x; acc[3][1] += a4.w * b4.y; acc[3][2] += a4.w * b4.z; acc[3][3] += a4.w * b4.w;
    }
  }

  float* Cdst;
  if constexpr (MODE == 0)      Cdst = p.Cout + (size_t)(split * 4 + z) * (BB * G4);
  else if constexpr (MODE == 1) Cdst = p.Cout + (size_t)(split * 2 + z) * (BB * 1024);
  else if constexpr (MODE == 2) Cdst = p.Cout + (size_t)z * (BB * TT * HH);
  else                          Cdst = p.Cout + (size_t)z * (BB * HH);
#pragma unroll
  for (int i = 0; i < 4; ++i) {
    const int row = m0 + (ty << 2) + i;
    float4 v;
    if constexpr (MODE == 3)
      v = make_float4(tanhf(acc[i][0]), tanhf(acc[i][1]), tanhf(acc[i][2]), tanhf(acc[i][3]));
    else
      v = make_float4(acc[i][0], acc[i][1], acc[i][2], acc[i][3]);
    *(float4*)&Cdst[(size_t)row * p.ldc + n0 + (tx << 2)] = v;
  }
}

// Pointwise LSTM gate update for all 4 runs. gates = [2 splits][4 runs][B][4H].
__global__ __launch_bounds__(256) void lstm_update(
    float* cbuf, float* hbuf, float* Ybuf, const float* gates,
    const float* b1, const float* b2, const int* s1, const int* s2, int t) {
  const int idx = blockIdx.x * 256 + threadIdx.x;   // (run*B + b)*H + m
  const int m = idx & (HH - 1);
  const int b = (idx >> 9) & (BB - 1);
  const int run = idx >> 16;
  const float* bias = (run & 1) ? b2 : b1;
  const int* sl = (run == 0 || run == 3) ? s1 : s2;
  const int goff = (run * BB + b) * G4;
  const float* g0 = gates + goff;
  const float* g1 = gates + 4 * BB * G4 + goff;
  const float gi = g0[m]          + g1[m]          + bias[m];
  const float gj = g0[HH + m]     + g1[HH + m]     + bias[HH + m];
  const float gf = g0[2 * HH + m] + g1[2 * HH + m] + bias[2 * HH + m];
  const float go = g0[3 * HH + m] + g1[3 * HH + m] + bias[3 * HH + m];
  const float c = cbuf[idx], h = hbuf[idx];
  const float cn = c * sigm(gf + 1.0f) + sigm(gi) * tanhf(gj);
  const float hn = tanhf(cn) * sigm(go);
  const bool v = t < sl[b];
  cbuf[idx] = v ? cn : c;
  hbuf[idx] = v ? hn : h;
  Ybuf[(size_t)((run * BB + b) * TT + t) * HH + m] = v ? hn : 0.0f;
}

// Per (asym, b): s[t'] = sum_h tanh(WyY+u)*wv ; masked softmax ; Y@alpha ; r_new = Y_alpha + tanh(r@Wt)
__global__ __launch_bounds__(256) void attn_mix(
    const float* WyY, const float* uv, const float* Ybuf, const float* wv,
    float* rbuf, float* rfin, const int* s1, const int* s2, int t) {
  const int a = blockIdx.y, b = blockIdx.x;
  const int tid = threadIdx.x;
  __shared__ float u_sh[HH], wv_sh[HH], s_sh[TT], alpha_sh[TT];
  const size_t ub = (size_t)(a * BB + b) * 1024;
  for (int i = tid; i < HH; i += 256) {
    float us = 0.f;
    for (int s = 0; s < 4; ++s) us += uv[(size_t)s * (2 * BB * 1024) + ub + i];
    u_sh[i] = us;
    wv_sh[i] = wv[i];
  }
  __syncthreads();
  const float* wy = WyY + (size_t)(a * BB + b) * TT * HH;
  const int wave = tid >> 6, lane = tid & 63;
  for (int it = 0; it < 16; ++it) {
    const int tp = (it << 2) + wave;
    const float* row = wy + tp * HH;
    float partial = 0.f;
#pragma unroll
    for (int q = 0; q < 8; ++q) {
      const int hh = lane + (q << 6);
      partial += tanhf(row[hh] + u_sh[hh]) * wv_sh[hh];
    }
    for (int off = 32; off; off >>= 1) partial += __shfl_down(partial, off);
    if (lane == 0) s_sh[tp] = partial;
  }
  __syncthreads();
  const int* smask = a ? s2 : s1;   // alpha mask over premise positions
  const int* ssnap = a ? s1 : s2;   // r_L selected at t == seq2-1
  if (tid < TT) {
    float sv = s_sh[tid] + (tid < smask[b] ? 0.f : NEGV);
    float mx = sv;
    for (int off = 32; off; off >>= 1) mx = fmaxf(mx, __shfl_xor(mx, off));
    const float e = expf(sv - mx);
    float sm = e;
    for (int off = 32; off; off >>= 1) sm += __shfl_xor(sm, off);
    alpha_sh[tid] = e / sm;
  }
  __syncthreads();
  const float* Yp = Ybuf + (size_t)((a ? 2 : 0) * BB + b) * TT * HH;
  for (int q = 0; q < 2; ++q) {
    const int hh = tid + (q << 8);
    float ya = 0.f;
    for (int tt2 = 0; tt2 < TT; ++tt2) ya += alpha_sh[tt2] * Yp[tt2 * HH + hh];
    float vsum = 0.f;
    for (int s = 0; s < 4; ++s) vsum += uv[(size_t)s * (2 * BB * 1024) + ub + HH + hh];
    const float rn = ya + tanhf(vsum);
    rbuf[(size_t)(a * BB + b) * HH + hh] = rn;
    if (t == ssnap[b] - 1) rfin[(size_t)(a * BB + b) * HH + hh] = rn;
  }
}

// Pack Bpack = [[Wh, 0],[Wr, Wt]] (1024x1024) and Wpx = [Wp; Wx] (1024x512)
__global__ void pack_k(const float* Wh, const float* Wr, const float* Wt,
                       const float* Wp, const float* Wx, float* Bpack, float* Wpx) {
  const int idx = blockIdx.x * 256 + threadIdx.x;
  if (idx < 1024 * 1024) {
    const int row = idx >> 10, col = idx & 1023;
    float v;
    if (row < HH) v = (col < HH) ? Wh[row * HH + col] : 0.f;
    else          v = (col < HH) ? Wr[(row - HH) * HH + col] : Wt[(row - HH) * HH + (col - HH)];
    Bpack[idx] = v;
  } else {
    const int i2 = idx - 1024 * 1024;
    const int row = i2 >> 9, col = i2 & 511;
    Wpx[i2] = (row < HH) ? Wp[row * HH + col] : Wx[(row - HH) * HH + col];
  }
}

__global__ void out_k(const float* lalb, const float* U, const float* bU, float* out) {
  const int tid = threadIdx.x;
  const int b = tid >> 1, j = tid & 1;
  float s = bU[j];
  for (int h = 0; h < HH; ++h)
    s += (lalb[b * HH + h] + lalb[BB * HH + b * HH + h]) * U[h * 2 + j];
  out[b * 2 + j] = s;
}

extern "C" void kernel_launch(void* const* d_in, const int* in_sizes, int n_in,
                              void* d_out, int out_size, void* d_ws, size_t ws_size,
                              hipStream_t stream) {
  const int* tok1 = (const int*)d_in[0];
  const int* tok2 = (const int*)d_in[1];
  const int* s1   = (const int*)d_in[2];
  const int* s2   = (const int*)d_in[3];
  const float* emb = (const float*)d_in[4];
  const float* W1 = (const float*)d_in[5];
  const float* b1 = (const float*)d_in[6];
  const float* W2 = (const float*)d_in[7];
  const float* b2 = (const float*)d_in[8];
  const float* Wy = (const float*)d_in[9];
  const float* Wh = (const float*)d_in[10];
  const float* Wr = (const float*)d_in[11];
  const float* wv = (const float*)d_in[12];
  const float* Wt = (const float*)d_in[13];
  const float* Wp = (const float*)d_in[14];
  const float* Wx = (const float*)d_in[15];
  const float* U  = (const float*)d_in[16];
  const float* bU = (const float*)d_in[17];
  float* ws = (float*)d_ws;

  // workspace layout (floats)
  float* cbuf  = ws;                                  // 4*B*H
  float* hbuf  = cbuf + 4 * BB * HH;                  // 4*B*H
  float* rbuf  = hbuf + 4 * BB * HH;                  // 2*B*H
  float* Ybuf  = rbuf + 2 * BB * HH;                  // 4*B*T*H
  float* gates = Ybuf + 4 * BB * TT * HH;             // 2 splits * 4*B*G4
  float* WyY   = gates + 2 * 4 * BB * G4;             // 2*B*T*H
  float* uvb   = WyY + 2 * BB * TT * HH;              // 4 splits * 2*B*1024
  float* rfin  = uvb + 4 * 2 * BB * 1024;             // 2*B*H
  float* Bpack = rfin + 2 * BB * HH;                  // 1024*1024
  float* Wpx   = Bpack + 1024 * 1024;                 // 1024*512
  float* lalb  = Wpx + 1024 * HH;                     // 2*B*H

  // zero c, h, r (contiguous head of ws)
  hipMemsetAsync(ws, 0, (size_t)(4 * BB * HH * 2 + 2 * BB * HH) * sizeof(float), stream);
  pack_k<<<6144, 256, 0, stream>>>(Wh, Wr, Wt, Wp, Wx, Bpack, Wpx);

  GP p{};
  p.emb = emb; p.tok1 = tok1; p.tok2 = tok2; p.W1 = W1; p.W2 = W2;
  p.hbuf = hbuf; p.Ybuf = Ybuf; p.rbuf = rbuf; p.rfin = rfin;

  // ---- 4 LSTMs, 64 sequential steps ----
  for (int t = 0; t < TT; ++t) {
    p.t = t; p.K = KL; p.ldb = G4; p.ldc = G4; p.Bp = nullptr; p.Cout = gates;
    gemm64<0, 2><<<dim3(32, 2, 8), 256, 0, stream>>>(p);          // 4 runs x 2 K-splits
    lstm_update<<<1024, 256, 0, stream>>>(cbuf, hbuf, Ybuf, gates, b1, b2, s1, s2, t);
  }

  // ---- WyY = Y_premise @ Wy for both asyms ----
  p.t = 0; p.K = HH; p.ldb = HH; p.ldc = HH; p.Bp = Wy; p.Cout = WyY;
  gemm64<2, 1><<<dim3(8, 128, 2), 256, 0, stream>>>(p);

  // ---- attention scans, 64 sequential steps ----
  for (int t = 0; t < TT; ++t) {
    p.t = t; p.K = 1024; p.ldb = 1024; p.ldc = 1024; p.Bp = Bpack; p.Cout = uvb;
    gemm64<1, 4><<<dim3(16, 2, 8), 256, 0, stream>>>(p);          // 2 asyms x 4 K-splits
    attn_mix<<<dim3(BB, 2), 256, 0, stream>>>(WyY, uvb, Ybuf, wv, rbuf, rfin, s1, s2, t);
  }

  // ---- la/lb = tanh([rfin | last_h] @ [Wp; Wx]) ----
  p.t = 0; p.K = 1024; p.ldb = HH; p.ldc = HH; p.Bp = Wpx; p.Cout = lalb;
  gemm64<3, 1><<<dim3(8, 2, 2), 256, 0, stream>>>(p);

  // ---- out = (la + lb) @ U + bU ----
  out_k<<<1, 256, 0, stream>>>(lalb, U, bU, (float*)d_out);
}

// Round 2
// 4945.165 us; speedup vs baseline: 1.5418x; 1.5418x over previous
//
#include <hip/hip_runtime.h>

typedef __attribute__((ext_vector_type(8))) short bf16x8;
typedef __attribute__((ext_vector_type(4))) float f32x4;

#define NB 128   // batch
#define NT 64    // time
#define ND 300   // emb dim
#define NH 512   // hidden
#define NG 2048  // 4H
#define KP0 832  // padded LSTM K: 320 (emb,pad) + 512 (h)

__device__ __forceinline__ float4 ld4(const float* p) { return *(const float4*)p; }
__device__ __forceinline__ unsigned short f2bf(float x) {
  unsigned int u = __float_as_uint(x);
  u += 0x7FFF + ((u >> 16) & 1);
  return (unsigned short)(u >> 16);
}
__device__ __forceinline__ float bf2f(unsigned short h) {
  return __uint_as_float(((unsigned int)h) << 16);
}
__device__ __forceinline__ float tanh_fast(float x) {
  x = fminf(fmaxf(x, -15.f), 15.f);
  const float e = __expf(2.f * x);
  return (e - 1.f) / (e + 1.f);
}
__device__ __forceinline__ float sigm(float x) { return 1.f / (1.f + __expf(-x)); }

struct GP {
  const float* emb; const int* tok1; const int* tok2;
  const float* hbuf; const float* rbuf; const float* Ybuf; const float* rfin;
  const unsigned short *B1h, *B1l, *B2h, *B2l;
  float* Cout; float* Cout2;
  int t;
};

// MFMA GEMM, 64x64 tile, 4 waves (2x2), per-wave 32x32 via 2x2 16x16x32 frags.
// bf16x3: acc += Al*Bh + Ah*Bl + Ah*Bh  (fp32-grade precision).
// MODE 0: LSTM gates  A=[emb(320 pad)|h] K=832, B=W1p/W2p, C=gates[512,2048]
// MODE 1: attn step   A=r[256,512],      B=[Wr|Wt]^T,      C=uv[256,1024]
// MODE 2: WyY/WhY2    A=Y runs,  K=512,  B=Wy^T/Wh^T,      C=WyY/WhY2 (z=0..3)
// MODE 3: final       A=[rfin|last_h] K=1024, B=[Wp;Wx]^T, C=tanh -> lalb[256,512]
template<int MODE>
__global__ __launch_bounds__(256) void gemm_mfma(GP p) {
  constexpr int KP  = (MODE == 0) ? KP0 : (MODE == 3) ? 1024 : 512;
  constexpr int NCH = KP / 32;
  constexpr int LDC = (MODE == 0) ? NG : (MODE == 1) ? 1024 : NH;

  const int n0 = blockIdx.x << 6, m0 = blockIdx.y << 6;
  const int z = blockIdx.z;
  const int tid = threadIdx.x;
  const int wave = tid >> 6, lane = tid & 63;
  const int wm = wave >> 1, wn = wave & 1;
  const int fr = lane & 15, kg = (lane >> 4) << 3;

  __shared__ __align__(16) unsigned short As[2][64][40];
  __shared__ __align__(16) unsigned short Bs[2][64][40];

  const int sr = tid >> 2;   // staging row (A) / col (B), 0..63
  const int sq = tid & 3;    // k-octet 0..3

  const int r_g = m0 + sr;
  int run = 0, bb = 0, token = 0;
  const float* Abase = nullptr;
  if constexpr (MODE == 0) {
    run = r_g >> 7; bb = r_g & 127;
    const int* tk = (run == 0 || run == 3) ? p.tok1 : p.tok2;
    token = tk[bb * NT + p.t];
  } else if constexpr (MODE == 1) {
    Abase = p.rbuf + (size_t)r_g * NH;
  } else if constexpr (MODE == 2) {
    const int runsel = (z == 0) ? 0 : (z == 1) ? 2 : (z == 2) ? 1 : 3;
    Abase = p.Ybuf + (size_t)runsel * (NB * NT * NH) + (size_t)r_g * NH;
  } else {
    run = r_g >> 7; bb = r_g & 127;
  }

  const unsigned short *Bh, *Bl;
  if constexpr (MODE == 0)      { Bh = (run & 1) ? p.B2h : p.B1h; Bl = (run & 1) ? p.B2l : p.B1l; }
  else if constexpr (MODE == 2) { Bh = (z < 2) ? p.B1h : p.B2h;   Bl = (z < 2) ? p.B1l : p.B2l; }
  else                          { Bh = p.B1h; Bl = p.B1l; }

  f32x4 acc[2][2];
#pragma unroll
  for (int mi = 0; mi < 2; ++mi)
#pragma unroll
    for (int ni = 0; ni < 2; ++ni) acc[mi][ni] = 0.f;

  for (int ch = 0; ch < NCH; ++ch) {
    const int k0 = ch << 5;
    // ---- A: 8 fp32 for (row sr, k = k0+sq*8 ..+7) ----
    float va[8];
    const int kq = k0 + (sq << 3);
#pragma unroll
    for (int g2 = 0; g2 < 2; ++g2) {
      const int k4 = kq + (g2 << 2);
      float4 v = make_float4(0.f, 0.f, 0.f, 0.f);
      if constexpr (MODE == 0) {
        if (k4 < 320) { if (k4 < ND) v = ld4(p.emb + (size_t)token * ND + k4); }
        else v = ld4(p.hbuf + (size_t)(run * NB + bb) * NH + (k4 - 320));
      } else if constexpr (MODE == 3) {
        if (k4 < NH) v = ld4(p.rfin + (size_t)r_g * NH + k4);
        else v = ld4(p.hbuf + (size_t)((run ? 3 : 1) * NB + bb) * NH + (k4 - NH));
      } else {
        v = ld4(Abase + k4);
      }
      va[g2 * 4 + 0] = v.x; va[g2 * 4 + 1] = v.y; va[g2 * 4 + 2] = v.z; va[g2 * 4 + 3] = v.w;
    }
    // ---- B: two 16B loads (hi/lo planes), col n0+sr ----
    const size_t boff = (size_t)(n0 + sr) * KP + k0 + (sq << 3);
    const bf16x8 bvh = *(const bf16x8*)(Bh + boff);
    const bf16x8 bvl = *(const bf16x8*)(Bl + boff);

    __syncthreads();
    bf16x8 ah, al;
#pragma unroll
    for (int i = 0; i < 8; ++i) {
      const float x = va[i];
      const unsigned short h = f2bf(x);
      ah[i] = (short)h;
      al[i] = (short)f2bf(x - bf2f(h));
    }
    *(bf16x8*)&As[0][sr][sq << 3] = ah;
    *(bf16x8*)&As[1][sr][sq << 3] = al;
    *(bf16x8*)&Bs[0][sr][sq << 3] = bvh;
    *(bf16x8*)&Bs[1][sr][sq << 3] = bvl;
    __syncthreads();

    bf16x8 Afh[2], Afl[2], Bfh[2], Bfl[2];
#pragma unroll
    for (int mi = 0; mi < 2; ++mi) {
      Afh[mi] = *(const bf16x8*)&As[0][wm * 32 + mi * 16 + fr][kg];
      Afl[mi] = *(const bf16x8*)&As[1][wm * 32 + mi * 16 + fr][kg];
    }
#pragma unroll
    for (int ni = 0; ni < 2; ++ni) {
      Bfh[ni] = *(const bf16x8*)&Bs[0][wn * 32 + ni * 16 + fr][kg];
      Bfl[ni] = *(const bf16x8*)&Bs[1][wn * 32 + ni * 16 + fr][kg];
    }
#pragma unroll
    for (int mi = 0; mi < 2; ++mi)
#pragma unroll
      for (int ni = 0; ni < 2; ++ni)
        acc[mi][ni] = __builtin_amdgcn_mfma_f32_16x16x32_bf16(Afl[mi], Bfh[ni], acc[mi][ni], 0, 0, 0);
#pragma unroll
    for (int mi = 0; mi < 2; ++mi)
#pragma unroll
      for (int ni = 0; ni < 2; ++ni)
        acc[mi][ni] = __builtin_amdgcn_mfma_f32_16x16x32_bf16(Afh[mi], Bfl[ni], acc[mi][ni], 0, 0, 0);
#pragma unroll
    for (int mi = 0; mi < 2; ++mi)
#pragma unroll
      for (int ni = 0; ni < 2; ++ni)
        acc[mi][ni] = __builtin_amdgcn_mfma_f32_16x16x32_bf16(Afh[mi], Bfh[ni], acc[mi][ni], 0, 0, 0);
  }

  float* Cd;
  if constexpr (MODE == 2)
    Cd = (z < 2) ? (p.Cout + (size_t)z * (NB * NT * NH)) : (p.Cout2 + (size_t)(z - 2) * (NB * NT * NH));
  else
    Cd = p.Cout;

#pragma unroll
  for (int mi = 0; mi < 2; ++mi)
#pragma unroll
    for (int ni = 0; ni < 2; ++ni) {
      const int row0 = m0 + wm * 32 + mi * 16 + ((lane >> 4) << 2);
      const int col = n0 + wn * 32 + ni * 16 + fr;
#pragma unroll
      for (int r = 0; r < 4; ++r) {
        float x = acc[mi][ni][r];
        if constexpr (MODE == 3) x = tanh_fast(x);
        Cd[(size_t)(row0 + r) * LDC + col] = x;
      }
    }
}

// Pointwise LSTM update, 4 runs, float4 per thread.
__global__ __launch_bounds__(256) void lstm_update(
    float* __restrict__ cbuf, float* __restrict__ hbuf, float* __restrict__ Ybuf,
    const float* __restrict__ gates, const float* __restrict__ b1, const float* __restrict__ b2,
    const int* __restrict__ s1, const int* __restrict__ s2, int t) {
  const int idx = blockIdx.x * 256 + threadIdx.x;
  const int m = (idx & 127) << 2;
  const int b = (idx >> 7) & 127;
  const int run = idx >> 14;
  const float* bias = (run & 1) ? b2 : b1;
  const int sl = ((run == 0 || run == 3) ? s1 : s2)[b];
  const float* g = gates + (size_t)(run * NB + b) * NG;
  const float4 gi = ld4(g + m),          bi = ld4(bias + m);
  const float4 gj = ld4(g + NH + m),     bj = ld4(bias + NH + m);
  const float4 gf = ld4(g + 2 * NH + m), bf_ = ld4(bias + 2 * NH + m);
  const float4 go = ld4(g + 3 * NH + m), bo = ld4(bias + 3 * NH + m);
  const size_t soff = (size_t)(run * NB + b) * NH + m;
  const float4 c4 = ld4(cbuf + soff);
  const float4 h4 = ld4(hbuf + soff);
  float cn[4], hn[4];
  const float gia[4] = {gi.x + bi.x, gi.y + bi.y, gi.z + bi.z, gi.w + bi.w};
  const float gja[4] = {gj.x + bj.x, gj.y + bj.y, gj.z + bj.z, gj.w + bj.w};
  const float gfa[4] = {gf.x + bf_.x, gf.y + bf_.y, gf.z + bf_.z, gf.w + bf_.w};
  const float goa[4] = {go.x + bo.x, go.y + bo.y, go.z + bo.z, go.w + bo.w};
  const float ca[4] = {c4.x, c4.y, c4.z, c4.w};
#pragma unroll
  for (int i = 0; i < 4; ++i) {
    cn[i] = ca[i] * sigm(gfa[i] + 1.f) + sigm(gia[i]) * tanh_fast(gja[i]);
    hn[i] = tanh_fast(cn[i]) * sigm(goa[i]);
  }
  const bool v = t < sl;
  float4 co = c4, ho = h4, yo = make_float4(0.f, 0.f, 0.f, 0.f);
  if (v) {
    co = make_float4(cn[0], cn[1], cn[2], cn[3]);
    ho = make_float4(hn[0], hn[1], hn[2], hn[3]);
    yo = ho;
  }
  *(float4*)(cbuf + soff) = co;
  *(float4*)(hbuf + soff) = ho;
  *(float4*)(Ybuf + (size_t)((run * NB + b) * NT + t) * NH + m) = yo;
}

// Per (asym,b): scores via tanh(WyY+u)*wv, masked softmax, Y@alpha, r update.
__global__ __launch_bounds__(256) void attn_mix(
    const float* __restrict__ WyY, const float* __restrict__ WhY2,
    const float* __restrict__ uv, const float* __restrict__ Ybuf,
    const float* __restrict__ wv, float* __restrict__ rbuf, float* __restrict__ rfin,
    const int* __restrict__ s1, const int* __restrict__ s2, int t) {
  const int a = blockIdx.y, b = blockIdx.x, tid = threadIdx.x;
  const int wave = tid >> 6, lane = tid & 63;
  __shared__ float4 u4[128], w4[128];
  __shared__ float s_sh[NT], alpha_sh[NT];
  const float* uvp = uv + (size_t)(a * NB + b) * 1024;
  const float* whp = WhY2 + ((size_t)a * NB * NT + (size_t)b * NT + t) * NH;
  if (tid < 128) {
    const float4 x = ld4(whp + tid * 4), y = ld4(uvp + tid * 4);
    u4[tid] = make_float4(x.x + y.x, x.y + y.y, x.z + y.z, x.w + y.w);
    w4[tid] = ld4(wv + tid * 4);
  }
  __syncthreads();
  const int sl = (a ? s2 : s1)[b];
  const float* wyb = WyY + ((size_t)a * NB * NT + (size_t)b * NT) * NH;
  for (int tp = wave; tp < NT; tp += 4) {
    float pt = 0.f;
    if (tp < sl) {
      const float* row = wyb + (size_t)tp * NH;
#pragma unroll
      for (int j2 = 0; j2 < 2; ++j2) {
        const int j = lane + j2 * 64;
        const float4 x = ld4(row + j * 4);
        const float4 u = u4[j], w = w4[j];
        pt += tanh_fast(x.x + u.x) * w.x + tanh_fast(x.y + u.y) * w.y
            + tanh_fast(x.z + u.z) * w.z + tanh_fast(x.w + u.w) * w.w;
      }
      for (int off = 32; off; off >>= 1) pt += __shfl_xor(pt, off, 64);
    }
    if (lane == 0) s_sh[tp] = (tp < sl) ? pt : -1e30f;
  }
  __syncthreads();
  if (tid < NT) {
    const float sv = s_sh[tid];
    float mx = sv;
    for (int off = 32; off; off >>= 1) mx = fmaxf(mx, __shfl_xor(mx, off, 64));
    const float e = (tid < sl) ? __expf(sv - mx) : 0.f;
    float sm = e;
    for (int off = 32; off; off >>= 1) sm += __shfl_xor(sm, off, 64);
    alpha_sh[tid] = e / sm;
  }
  __syncthreads();
  const int runY = a ? 2 : 0;
  const float* Yp = Ybuf + (size_t)(runY * NB + b) * NT * NH;
  const int snap = (a ? s1 : s2)[b] - 1;
#pragma unroll
  for (int q2 = 0; q2 < 2; ++q2) {
    const int hh = tid + q2 * 256;
    float ya = 0.f;
    for (int tp = 0; tp < sl; ++tp) ya += alpha_sh[tp] * Yp[(size_t)tp * NH + hh];
    const float rn = ya + tanh_fast(uvp[NH + hh]);
    rbuf[(size_t)(a * NB + b) * NH + hh] = rn;
    if (t == snap) rfin[(size_t)(a * NB + b) * NH + hh] = rn;
  }
}

// One-time pack: bf16 hi/lo splits, B^T layouts.
__global__ __launch_bounds__(256) void pack_k(
    const float* __restrict__ W1, const float* __restrict__ W2,
    const float* __restrict__ Wy, const float* __restrict__ Wh,
    const float* __restrict__ Wr, const float* __restrict__ Wt,
    const float* __restrict__ Wp, const float* __restrict__ Wx,
    unsigned short* W1h, unsigned short* W1l, unsigned short* W2h, unsigned short* W2l,
    unsigned short* Wyh, unsigned short* Wyl, unsigned short* Whh, unsigned short* Whl,
    unsigned short* Wrh, unsigned short* Wrl, unsigned short* Wph, unsigned short* Wpl) {
  const int idx = blockIdx.x * 256 + threadIdx.x;
  const int SZW = 2048 * 832, SZS = 512 * 512, SZR = 1024 * 512, SZP = 512 * 1024;
  float v; unsigned short *dh, *dl; int di;
  if (idx < 2 * SZW) {
    const float* W = (idx < SZW) ? W1 : W2;
    di = (idx < SZW) ? idx : idx - SZW;
    const int n = di / 832, k = di % 832;
    v = (k < 320) ? ((k < ND) ? W[(size_t)k * NG + n] : 0.f) : W[(size_t)(k - 20) * NG + n];
    dh = (idx < SZW) ? W1h : W2h; dl = (idx < SZW) ? W1l : W2l;
  } else if (idx < 2 * SZW + 2 * SZS) {
    const int i2 = idx - 2 * SZW;
    const float* W = (i2 < SZS) ? Wy : Wh;
    di = (i2 < SZS) ? i2 : i2 - SZS;
    const int n = di >> 9, k = di & 511;
    v = W[(size_t)k * NH + n];
    dh = (i2 < SZS) ? Wyh : Whh; dl = (i2 < SZS) ? Wyl : Whl;
  } else if (idx < 2 * SZW + 2 * SZS + SZR) {
    di = idx - 2 * SZW - 2 * SZS;
    const int n = di >> 9, k = di & 511;
    v = (n < NH) ? Wr[(size_t)k * NH + n] : Wt[(size_t)k * NH + (n - NH)];
    dh = Wrh; dl = Wrl;
  } else {
    di = idx - 2 * SZW - 2 * SZS - SZR;
    const int n = di >> 10, k = di & 1023;
    v = (k < NH) ? Wp[(size_t)k * NH + n] : Wx[(size_t)(k - NH) * NH + n];
    dh = Wph; dl = Wpl;
  }
  const unsigned short h = f2bf(v);
  dh[di] = h;
  dl[di] = f2bf(v - bf2f(h));
}

__global__ void out_k(const float* __restrict__ lalb, const float* __restrict__ U,
                      const float* __restrict__ bU, float* __restrict__ out) {
  const int tid = threadIdx.x;
  const int b = tid >> 1, j = tid & 1;
  float s = bU[j];
  for (int h = 0; h < NH; ++h)
    s += (lalb[b * NH + h] + lalb[NB * NH + b * NH + h]) * U[h * 2 + j];
  out[b * 2 + j] = s;
}

extern "C" void kernel_launch(void* const* d_in, const int* in_sizes, int n_in,
                              void* d_out, int out_size, void* d_ws, size_t ws_size,
                              hipStream_t stream) {
  const int* tok1 = (const int*)d_in[0];
  const int* tok2 = (const int*)d_in[1];
  const int* s1   = (const int*)d_in[2];
  const int* s2   = (const int*)d_in[3];
  const float* emb = (const float*)d_in[4];
  const float* W1 = (const float*)d_in[5];
  const float* b1 = (const float*)d_in[6];
  const float* W2 = (const float*)d_in[7];
  const float* b2 = (const float*)d_in[8];
  const float* Wy = (const float*)d_in[9];
  const float* Wh = (const float*)d_in[10];
  const float* Wr = (const float*)d_in[11];
  const float* wv = (const float*)d_in[12];
  const float* Wt = (const float*)d_in[13];
  const float* Wp = (const float*)d_in[14];
  const float* Wx = (const float*)d_in[15];
  const float* U  = (const float*)d_in[16];
  const float* bU = (const float*)d_in[17];

  float* ws = (float*)d_ws;
  float* cbuf  = ws;                        // 262144
  float* hbuf  = cbuf + 262144;             // 262144
  float* rbuf  = hbuf + 262144;             // 131072
  float* Ybuf  = rbuf + 131072;             // 16777216
  float* gates = Ybuf + 16777216;           // 1048576
  float* WyY   = gates + 1048576;           // 8388608
  float* WhY2  = WyY + 8388608;             // 8388608
  float* uv    = WhY2 + 8388608;            // 262144
  float* rfin  = uv + 262144;               // 131072
  float* lalb  = rfin + 131072;             // 131072
  unsigned short* pk = (unsigned short*)(lalb + 131072);
  const int SZW = 2048 * 832, SZS = 512 * 512, SZR = 1024 * 512, SZP = 512 * 1024;
  unsigned short* W1h = pk;            unsigned short* W1l = W1h + SZW;
  unsigned short* W2h = W1l + SZW;     unsigned short* W2l = W2h + SZW;
  unsigned short* Wyh = W2l + SZW;     unsigned short* Wyl = Wyh + SZS;
  unsigned short* Whh = Wyl + SZS;     unsigned short* Whl = Whh + SZS;
  unsigned short* Wrh = Whl + SZS;     unsigned short* Wrl = Wrh + SZR;
  unsigned short* Wph = Wrl + SZR;     unsigned short* Wpl = Wph + SZP;

  hipMemsetAsync(ws, 0, (size_t)(262144 + 262144 + 131072) * sizeof(float), stream);
  pack_k<<<19456, 256, 0, stream>>>(W1, W2, Wy, Wh, Wr, Wt, Wp, Wx,
                                    W1h, W1l, W2h, W2l, Wyh, Wyl, Whh, Whl,
                                    Wrh, Wrl, Wph, Wpl);

  GP p{};
  p.emb = emb; p.tok1 = tok1; p.tok2 = tok2;
  p.hbuf = hbuf; p.rbuf = rbuf; p.Ybuf = Ybuf; p.rfin = rfin;

  // ---- 4 LSTMs, 64 sequential steps ----
  for (int t = 0; t < NT; ++t) {
    p.t = t;
    p.B1h = W1h; p.B1l = W1l; p.B2h = W2h; p.B2l = W2l;
    p.Cout = gates;
    gemm_mfma<0><<<dim3(32, 8, 1), 256, 0, stream>>>(p);
    lstm_update<<<256, 256, 0, stream>>>(cbuf, hbuf, Ybuf, gates, b1, b2, s1, s2, t);
  }

  // ---- WyY (z=0,1) and WhY2 (z=2,3) ----
  p.B1h = Wyh; p.B1l = Wyl; p.B2h = Whh; p.B2l = Whl;
  p.Cout = WyY; p.Cout2 = WhY2;
  gemm_mfma<2><<<dim3(8, 128, 4), 256, 0, stream>>>(p);

  // ---- attention scans, 64 sequential steps ----
  for (int t = 0; t < NT; ++t) {
    p.t = t;
    p.B1h = Wrh; p.B1l = Wrl;
    p.Cout = uv;
    gemm_mfma<1><<<dim3(16, 4, 1), 256, 0, stream>>>(p);
    attn_mix<<<dim3(NB, 2), 256, 0, stream>>>(WyY, WhY2, uv, Ybuf, wv, rbuf, rfin, s1, s2, t);
  }

  // ---- la/lb = tanh([rfin | last_h] @ [Wp; Wx]) ----
  p.B1h = Wph; p.B1l = Wpl;
  p.Cout = lalb;
  gemm_mfma<3><<<dim3(8, 4, 1), 256, 0, stream>>>(p);

  out_k<<<1, 256, 0, stream>>>(lalb, U, bU, (float*)d_out);
}